// Round 10
// baseline (95.431 us; speedup 1.0000x reference)
//
#include <hip/hip_runtime.h>

namespace {

constexpr int Tt = 32;    // frames (t)
constexpr int Ss = 784;   // floats per row (h*w)

using bf16x8 = __attribute__((ext_vector_type(8))) short;
using f32x4  = __attribute__((ext_vector_type(4))) float;

// split fp32 -> hi (truncated bf16) + lo (bf16 of residual); pack 2 per uint
__device__ inline void cvt2(float a, float b, unsigned& h, unsigned& l) {
  const unsigned ha = __float_as_uint(a) >> 16;
  const unsigned hb = __float_as_uint(b) >> 16;
  const float ra = a - __uint_as_float(ha << 16);
  const float rb = b - __uint_as_float(hb << 16);
  const unsigned la = __float_as_uint(ra) >> 16;
  const unsigned lb = __float_as_uint(rb) >> 16;
  h = ha | (hb << 16);
  l = la | (lb << 16);
}

// ---------------------------------------------------------------------------
// Kernel 1: per-(b,c) Gram via split-bf16 MFMA, DIRECT-GLOBAL fragments.
//   part[bc][q*32+k] = sum_s x[bc][q][s]*x[bc][k][s]
// 1024 blocks x 256 threads (4 waves), LDS only for the 16.9 KB epilogue.
// A-frag layout (validated r7/r9): lane (col,g) holds x[row][ks*32+8g..+7]
// — CONTIGUOUS in s -> two coalesced float4 global loads per operand half.
// h0/l0 = rows 0-15 (row=col), h1/l1 = rows 16-31. Wave w owns ksteps
// ks % 4 == w (25 ksteps; ks=24 is the s>=784 zero-pad, per-lane predicated).
// No staging, no main-loop barriers. C = HI*HI^T + HI*LO^T + LO*HI^T.
// ---------------------------------------------------------------------------
__global__ __launch_bounds__(256, 4) void gram_partial(const float* __restrict__ x,
                                                       float* __restrict__ part) {
  const int bc = blockIdx.x;                       // b*64 + c
  const float* __restrict__ xb = x + (size_t)bc * (Tt * Ss);
  const int tid  = threadIdx.x;
  const int w    = tid >> 6;          // wave 0..3
  const int lane = tid & 63;
  const int col  = lane & 15;
  const int g    = lane >> 4;

  f32x4 d1[2][2], d2[2][2], d3[2][2];
#pragma unroll
  for (int i = 0; i < 2; ++i)
#pragma unroll
    for (int j = 0; j < 2; ++j) { d1[i][j] = 0.f; d2[i][j] = 0.f; d3[i][j] = 0.f; }

  const float* __restrict__ pa = xb + (size_t)col * Ss;         // rows 0-15
  const float* __restrict__ pb = xb + (size_t)(16 + col) * Ss;  // rows 16-31

  for (int ks = w; ks < 25; ks += 4) {
    const int s0 = ks * 32 + g * 8;
    uint4 ha = {0u,0u,0u,0u}, la = {0u,0u,0u,0u};
    uint4 hb = {0u,0u,0u,0u}, lb = {0u,0u,0u,0u};
    if (s0 < 784) {                       // s0 is a multiple of 8; s0<=776 => s0+7 valid
      const float4 a0 = *reinterpret_cast<const float4*>(pa + s0);
      const float4 a1 = *reinterpret_cast<const float4*>(pa + s0 + 4);
      const float4 b0 = *reinterpret_cast<const float4*>(pb + s0);
      const float4 b1 = *reinterpret_cast<const float4*>(pb + s0 + 4);
      cvt2(a0.x, a0.y, ha.x, la.x);
      cvt2(a0.z, a0.w, ha.y, la.y);
      cvt2(a1.x, a1.y, ha.z, la.z);
      cvt2(a1.z, a1.w, ha.w, la.w);
      cvt2(b0.x, b0.y, hb.x, lb.x);
      cvt2(b0.z, b0.w, hb.y, lb.y);
      cvt2(b1.x, b1.y, hb.z, lb.z);
      cvt2(b1.z, b1.w, hb.w, lb.w);
    }
    const bf16x8 h0 = __builtin_bit_cast(bf16x8, ha);
    const bf16x8 l0 = __builtin_bit_cast(bf16x8, la);
    const bf16x8 h1 = __builtin_bit_cast(bf16x8, hb);
    const bf16x8 l1 = __builtin_bit_cast(bf16x8, lb);
    d1[0][0] = __builtin_amdgcn_mfma_f32_16x16x32_bf16(h0, h0, d1[0][0], 0, 0, 0);
    d1[0][1] = __builtin_amdgcn_mfma_f32_16x16x32_bf16(h0, h1, d1[0][1], 0, 0, 0);
    d1[1][0] = __builtin_amdgcn_mfma_f32_16x16x32_bf16(h1, h0, d1[1][0], 0, 0, 0);
    d1[1][1] = __builtin_amdgcn_mfma_f32_16x16x32_bf16(h1, h1, d1[1][1], 0, 0, 0);
    d2[0][0] = __builtin_amdgcn_mfma_f32_16x16x32_bf16(h0, l0, d2[0][0], 0, 0, 0);
    d2[0][1] = __builtin_amdgcn_mfma_f32_16x16x32_bf16(h0, l1, d2[0][1], 0, 0, 0);
    d2[1][0] = __builtin_amdgcn_mfma_f32_16x16x32_bf16(h1, l0, d2[1][0], 0, 0, 0);
    d2[1][1] = __builtin_amdgcn_mfma_f32_16x16x32_bf16(h1, l1, d2[1][1], 0, 0, 0);
    d3[0][0] = __builtin_amdgcn_mfma_f32_16x16x32_bf16(l0, h0, d3[0][0], 0, 0, 0);
    d3[0][1] = __builtin_amdgcn_mfma_f32_16x16x32_bf16(l0, h1, d3[0][1], 0, 0, 0);
    d3[1][0] = __builtin_amdgcn_mfma_f32_16x16x32_bf16(l1, h0, d3[1][0], 0, 0, 0);
    d3[1][1] = __builtin_amdgcn_mfma_f32_16x16x32_bf16(l1, h1, d3[1][1], 0, 0, 0);
  }

  // ---- epilogue: combine D1+D2+D3, reduce over 4 waves (LDS, 1 barrier) ----
  __shared__ float mtmp[4 * 1056];    // 16896 B
#pragma unroll
  for (int i = 0; i < 2; ++i)
#pragma unroll
    for (int j = 0; j < 2; ++j) {
      const f32x4 s4 = d1[i][j] + d2[i][j] + d3[i][j];
#pragma unroll
      for (int r = 0; r < 4; ++r) {
        const int row = i * 16 + g * 4 + r;       // m89-verified C/D map
        const int cc  = j * 16 + col;
        mtmp[w * 1056 + row * 33 + cc] = s4[r];
      }
    }
  __syncthreads();

  const int e0 = tid * 4;
  float tmp[4];
#pragma unroll
  for (int u = 0; u < 4; ++u) {
    const int row = (e0 + u) >> 5;
    const int cc  = (e0 + u) & 31;
    float ss = 0.f;
#pragma unroll
    for (int ww = 0; ww < 4; ++ww) ss += mtmp[ww * 1056 + row * 33 + cc];
    tmp[u] = ss;
  }
  float4 o4;
  o4.x = tmp[0]; o4.y = tmp[1]; o4.z = tmp[2]; o4.w = tmp[3];
  *reinterpret_cast<float4*>(part + (size_t)bc * 1024 + e0) = o4;
}

// ---------------------------------------------------------------------------
// Kernel 2: reduce partials over c.  msum[b][e] = sum_c part[b*64+c][e]
// ---------------------------------------------------------------------------
__global__ __launch_bounds__(256) void reduce_c(const float* __restrict__ part,
                                                float* __restrict__ msum) {
  const int bid = blockIdx.x;                // 0..63
  const int b   = bid >> 2;
  const int e   = (bid & 3) * 256 + threadIdx.x;   // 0..1023
  const float* __restrict__ p = part + (size_t)b * 64 * 1024 + e;
  float s0 = 0.f, s1 = 0.f, s2 = 0.f, s3 = 0.f;
#pragma unroll
  for (int c = 0; c < 64; c += 4) {
    s0 += p[(size_t)(c + 0) * 1024];
    s1 += p[(size_t)(c + 1) * 1024];
    s2 += p[(size_t)(c + 2) * 1024];
    s3 += p[(size_t)(c + 3) * 1024];
  }
  msum[b * 1024 + e] = (s0 + s1) + (s2 + s3);
}

// ---------------------------------------------------------------------------
// Kernel 3: softmax over the BATCH axis. Output q-major: mq[b][q*32+k].
// ---------------------------------------------------------------------------
__global__ __launch_bounds__(256) void softmax_b(const float* __restrict__ msum,
                                                 float* __restrict__ mq) {
  const int e = blockIdx.x * 256 + threadIdx.x;    // q*32 + k
  float l[16];
  float mx = -3.4e38f;
#pragma unroll
  for (int b = 0; b < 16; ++b) {
    l[b] = msum[b * 1024 + e];
    mx = fmaxf(mx, l[b]);
  }
  float s = 0.f;
#pragma unroll
  for (int b = 0; b < 16; ++b) {
    l[b] = expf(l[b] - mx);
    s += l[b];
  }
  const float inv = 1.f / s;
#pragma unroll
  for (int b = 0; b < 16; ++b) mq[b * 1024 + e] = l[b] * inv;
}

// ---------------------------------------------------------------------------
// Kernel 4: PV via split-bf16 MFMA, NO LDS, NO BARRIERS.
//   out[bc] = M[b] (32x32) * xv[bc] (32x784)
// 1024 blocks x 256 threads (4 waves). 49 column-frags of 16; wave w owns
// frags [12w, 12w+12) (contiguous -> adjacent frags share 128B lines via L1),
// wave 3 also takes frag 48. Per frag: 8 k-strided dword loads (validated
// B-frag layout, r9 tail path), cvt -> vh/vl, 3 MFMA x 2 q-frags, 8 stores.
// Fully unrolled -> deep load pipelining, no sync anywhere.
// ---------------------------------------------------------------------------
__global__ __launch_bounds__(256, 4) void pv(const float* __restrict__ xv,
                                             const float* __restrict__ mq,
                                             float* __restrict__ out) {
  const int bc = blockIdx.x;                  // b*64 + c
  const int b  = bc >> 6;
  const float* __restrict__ xvb = xv + (size_t)bc * (Tt * Ss);
  float* __restrict__ ob        = out + (size_t)bc * (Tt * Ss);

  const int tid  = threadIdx.x;
  const int w    = tid >> 6;                  // wave 0..3
  const int lane = tid & 63;
  const int col  = lane & 15;                 // frag column / M row
  const int g    = lane >> 4;                 // k-group (k = 8g..8g+7)

  // ---- M fragments (once per block; mq is L2-hot) ----
  bf16x8 mh[2], ml[2];
#pragma unroll
  for (int qf = 0; qf < 2; ++qf) {
    const float* mp = mq + b * 1024 + (qf * 16 + col) * 32 + g * 8;
    const float4 ma = *reinterpret_cast<const float4*>(mp);
    const float4 mb = *reinterpret_cast<const float4*>(mp + 4);
    uint4 h, l;
    cvt2(ma.x, ma.y, h.x, l.x);
    cvt2(ma.z, ma.w, h.y, l.y);
    cvt2(mb.x, mb.y, h.z, l.z);
    cvt2(mb.z, mb.w, h.w, l.w);
    mh[qf] = __builtin_bit_cast(bf16x8, h);
    ml[qf] = __builtin_bit_cast(bf16x8, l);
  }

  auto do_frag = [&](int sf) {
    float f8[8];
#pragma unroll
    for (int j = 0; j < 8; ++j)
      f8[j] = xvb[(size_t)(8 * g + j) * Ss + sf * 16 + col];
    uint4 hh, lv;
    cvt2(f8[0], f8[1], hh.x, lv.x);
    cvt2(f8[2], f8[3], hh.y, lv.y);
    cvt2(f8[4], f8[5], hh.z, lv.z);
    cvt2(f8[6], f8[7], hh.w, lv.w);
    const bf16x8 vh = __builtin_bit_cast(bf16x8, hh);
    const bf16x8 vl = __builtin_bit_cast(bf16x8, lv);
    const int s = sf * 16 + col;
#pragma unroll
    for (int qf = 0; qf < 2; ++qf) {
      f32x4 d = {0.f, 0.f, 0.f, 0.f};
      d = __builtin_amdgcn_mfma_f32_16x16x32_bf16(mh[qf], vl, d, 0, 0, 0);
      d = __builtin_amdgcn_mfma_f32_16x16x32_bf16(ml[qf], vh, d, 0, 0, 0);
      d = __builtin_amdgcn_mfma_f32_16x16x32_bf16(mh[qf], vh, d, 0, 0, 0);
#pragma unroll
      for (int r = 0; r < 4; ++r)
        ob[(size_t)(qf * 16 + g * 4 + r) * Ss + s] = d[r];   // m89 C/D map
    }
  };

  const int f0 = w * 12;
#pragma unroll
  for (int i = 0; i < 12; ++i) do_frag(f0 + i);
  if (w == 3) do_frag(48);
}

}  // namespace

extern "C" void kernel_launch(void* const* d_in, const int* in_sizes, int n_in,
                              void* d_out, int out_size, void* d_ws, size_t ws_size,
                              hipStream_t stream) {
  const float* x  = (const float*)d_in[0];
  const float* xv = (const float*)d_in[1];
  float* out = (float*)d_out;

  // workspace (fp32), ~4.2 MiB total:
  float* part = (float*)d_ws;            // 1024 x 1024
  float* msum = part + 1024 * 1024;      // 16 x 1024
  float* mq   = msum + 16 * 1024;        // 16 x 1024 (q-major softmax weights)

  gram_partial<<<dim3(1024), dim3(256), 0, stream>>>(x, part);
  reduce_c<<<dim3(64), dim3(256), 0, stream>>>(part, msum);
  softmax_b<<<dim3(4), dim3(256), 0, stream>>>(msum, mq);
  pv<<<dim3(1024), dim3(256), 0, stream>>>(xv, mq, out);
}

// Round 11
// 82.518 us; speedup vs baseline: 1.1565x; 1.1565x over previous
//
#include <hip/hip_runtime.h>

namespace {

constexpr int Tt = 32;    // frames (t)
constexpr int Ss = 784;   // floats per row (h*w)

using bf16x8 = __attribute__((ext_vector_type(8))) short;
using f32x4  = __attribute__((ext_vector_type(4))) float;

// split fp32 -> hi (truncated bf16) + lo (bf16 of residual); pack 2 per uint
__device__ inline void cvt2(float a, float b, unsigned& h, unsigned& l) {
  const unsigned ha = __float_as_uint(a) >> 16;
  const unsigned hb = __float_as_uint(b) >> 16;
  const float ra = a - __uint_as_float(ha << 16);
  const float rb = b - __uint_as_float(hb << 16);
  const unsigned la = __float_as_uint(ra) >> 16;
  const unsigned lb = __float_as_uint(rb) >> 16;
  h = ha | (hb << 16);
  l = la | (lb << 16);
}

// async global->LDS, 16 B per lane; LDS dest must be wave-uniform base.
__device__ inline void gload16(const float* g, float* l) {
  __builtin_amdgcn_global_load_lds(
      (const __attribute__((address_space(1))) void*)g,
      (__attribute__((address_space(3))) void*)l, 16, 0, 0);
}

// ---------------------------------------------------------------------------
// Kernel 1: per-(b,c) Gram via split-bf16 MFMA, direct-global fragments
// (unchanged from round 10; ~22 us vs 16.4 us HBM floor).
// ---------------------------------------------------------------------------
__global__ __launch_bounds__(256, 4) void gram_partial(const float* __restrict__ x,
                                                       float* __restrict__ part) {
  const int bc = blockIdx.x;                       // b*64 + c
  const float* __restrict__ xb = x + (size_t)bc * (Tt * Ss);
  const int tid  = threadIdx.x;
  const int w    = tid >> 6;          // wave 0..3
  const int lane = tid & 63;
  const int col  = lane & 15;
  const int g    = lane >> 4;

  f32x4 d1[2][2], d2[2][2], d3[2][2];
#pragma unroll
  for (int i = 0; i < 2; ++i)
#pragma unroll
    for (int j = 0; j < 2; ++j) { d1[i][j] = 0.f; d2[i][j] = 0.f; d3[i][j] = 0.f; }

  const float* __restrict__ pa = xb + (size_t)col * Ss;         // rows 0-15
  const float* __restrict__ pb = xb + (size_t)(16 + col) * Ss;  // rows 16-31

  for (int ks = w; ks < 25; ks += 4) {
    const int s0 = ks * 32 + g * 8;
    uint4 ha = {0u,0u,0u,0u}, la = {0u,0u,0u,0u};
    uint4 hb = {0u,0u,0u,0u}, lb = {0u,0u,0u,0u};
    if (s0 < 784) {
      const float4 a0 = *reinterpret_cast<const float4*>(pa + s0);
      const float4 a1 = *reinterpret_cast<const float4*>(pa + s0 + 4);
      const float4 b0 = *reinterpret_cast<const float4*>(pb + s0);
      const float4 b1 = *reinterpret_cast<const float4*>(pb + s0 + 4);
      cvt2(a0.x, a0.y, ha.x, la.x);
      cvt2(a0.z, a0.w, ha.y, la.y);
      cvt2(a1.x, a1.y, ha.z, la.z);
      cvt2(a1.z, a1.w, ha.w, la.w);
      cvt2(b0.x, b0.y, hb.x, lb.x);
      cvt2(b0.z, b0.w, hb.y, lb.y);
      cvt2(b1.x, b1.y, hb.z, lb.z);
      cvt2(b1.z, b1.w, hb.w, lb.w);
    }
    const bf16x8 h0 = __builtin_bit_cast(bf16x8, ha);
    const bf16x8 l0 = __builtin_bit_cast(bf16x8, la);
    const bf16x8 h1 = __builtin_bit_cast(bf16x8, hb);
    const bf16x8 l1 = __builtin_bit_cast(bf16x8, lb);
    d1[0][0] = __builtin_amdgcn_mfma_f32_16x16x32_bf16(h0, h0, d1[0][0], 0, 0, 0);
    d1[0][1] = __builtin_amdgcn_mfma_f32_16x16x32_bf16(h0, h1, d1[0][1], 0, 0, 0);
    d1[1][0] = __builtin_amdgcn_mfma_f32_16x16x32_bf16(h1, h0, d1[1][0], 0, 0, 0);
    d1[1][1] = __builtin_amdgcn_mfma_f32_16x16x32_bf16(h1, h1, d1[1][1], 0, 0, 0);
    d2[0][0] = __builtin_amdgcn_mfma_f32_16x16x32_bf16(h0, l0, d2[0][0], 0, 0, 0);
    d2[0][1] = __builtin_amdgcn_mfma_f32_16x16x32_bf16(h0, l1, d2[0][1], 0, 0, 0);
    d2[1][0] = __builtin_amdgcn_mfma_f32_16x16x32_bf16(h1, l0, d2[1][0], 0, 0, 0);
    d2[1][1] = __builtin_amdgcn_mfma_f32_16x16x32_bf16(h1, l1, d2[1][1], 0, 0, 0);
    d3[0][0] = __builtin_amdgcn_mfma_f32_16x16x32_bf16(l0, h0, d3[0][0], 0, 0, 0);
    d3[0][1] = __builtin_amdgcn_mfma_f32_16x16x32_bf16(l0, h1, d3[0][1], 0, 0, 0);
    d3[1][0] = __builtin_amdgcn_mfma_f32_16x16x32_bf16(l1, h0, d3[1][0], 0, 0, 0);
    d3[1][1] = __builtin_amdgcn_mfma_f32_16x16x32_bf16(l1, h1, d3[1][1], 0, 0, 0);
  }

  // ---- epilogue: combine D1+D2+D3, reduce over 4 waves (LDS, 1 barrier) ----
  __shared__ float mtmp[4 * 1056];    // 16896 B
#pragma unroll
  for (int i = 0; i < 2; ++i)
#pragma unroll
    for (int j = 0; j < 2; ++j) {
      const f32x4 s4 = d1[i][j] + d2[i][j] + d3[i][j];
#pragma unroll
      for (int r = 0; r < 4; ++r) {
        const int row = i * 16 + g * 4 + r;       // m89-verified C/D map
        const int cc  = j * 16 + col;
        mtmp[w * 1056 + row * 33 + cc] = s4[r];
      }
    }
  __syncthreads();

  const int e0 = tid * 4;
  float tmp[4];
#pragma unroll
  for (int u = 0; u < 4; ++u) {
    const int row = (e0 + u) >> 5;
    const int cc  = (e0 + u) & 31;
    float ss = 0.f;
#pragma unroll
    for (int ww = 0; ww < 4; ++ww) ss += mtmp[ww * 1056 + row * 33 + cc];
    tmp[u] = ss;
  }
  float4 o4;
  o4.x = tmp[0]; o4.y = tmp[1]; o4.z = tmp[2]; o4.w = tmp[3];
  *reinterpret_cast<float4*>(part + (size_t)bc * 1024 + e0) = o4;
}

// ---------------------------------------------------------------------------
// Kernel 2: reduce partials over c.  msum[b][e] = sum_c part[b*64+c][e]
// ---------------------------------------------------------------------------
__global__ __launch_bounds__(256) void reduce_c(const float* __restrict__ part,
                                                float* __restrict__ msum) {
  const int bid = blockIdx.x;                // 0..63
  const int b   = bid >> 2;
  const int e   = (bid & 3) * 256 + threadIdx.x;   // 0..1023
  const float* __restrict__ p = part + (size_t)b * 64 * 1024 + e;
  float s0 = 0.f, s1 = 0.f, s2 = 0.f, s3 = 0.f;
#pragma unroll
  for (int c = 0; c < 64; c += 4) {
    s0 += p[(size_t)(c + 0) * 1024];
    s1 += p[(size_t)(c + 1) * 1024];
    s2 += p[(size_t)(c + 2) * 1024];
    s3 += p[(size_t)(c + 3) * 1024];
  }
  msum[b * 1024 + e] = (s0 + s1) + (s2 + s3);
}

// ---------------------------------------------------------------------------
// Kernel 3: softmax over the BATCH axis + transpose to [k][q]-major.
// ---------------------------------------------------------------------------
__global__ __launch_bounds__(256) void softmax_b(const float* __restrict__ msum,
                                                 float* __restrict__ mt) {
  const int e = blockIdx.x * 256 + threadIdx.x;    // q*32 + k
  float l[16];
  float mx = -3.4e38f;
#pragma unroll
  for (int b = 0; b < 16; ++b) {
    l[b] = msum[b * 1024 + e];
    mx = fmaxf(mx, l[b]);
  }
  float s = 0.f;
#pragma unroll
  for (int b = 0; b < 16; ++b) {
    l[b] = expf(l[b] - mx);
    s += l[b];
  }
  const float inv = 1.f / s;
  const int et = (e & 31) * 32 + (e >> 5);         // k*32 + q
#pragma unroll
  for (int b = 0; b < 16; ++b) mt[b * 1024 + et] = l[b] * inv;
}

// ---------------------------------------------------------------------------
// Kernel 4: PV, fp32 VALU + scalar-pipe M (r7's validated math) fed by
// global_load_lds double-buffered staging (zero-VGPR async loads -> whole
// 25 KB chunk in flight; compiler cannot serialize it).
// 1024 blocks x 256 threads (4 waves), LDS 2 x 32x196 fp32 = 50176 B
// -> 3 blocks/CU. 784 = 4 x 196: no tail. Wave w: q rows 8w..8w+7;
// lane < 49 owns one float4 column. Per k: 1 ds_read_b128 + 8 s_load-backed
// FMAs. Stage(ch+1) issued BEFORE compute(ch); __syncthreads() drains vmcnt.
// ---------------------------------------------------------------------------
__global__ __launch_bounds__(256, 3) void pv(const float* __restrict__ xv,
                                             const float* __restrict__ mt,
                                             float* __restrict__ out) {
  const int bc = blockIdx.x;                  // b*64 + c
  const int b  = bc >> 6;
  const float* __restrict__ xvb = xv + (size_t)bc * (Tt * Ss);
  float* __restrict__ ob        = out + (size_t)bc * (Tt * Ss);

  const int tid  = threadIdx.x;
  const int w    = tid >> 6;
  const int lane = tid & 63;

  __shared__ float lds[2 * 6272];             // 2 x 25088 B

  // stage chunk ch (32 rows x 196 floats) into lbuf: 1568 x 16B transfers,
  // slot v = row*49 + c4; LDS base wave-uniform, global addr per-lane.
  auto stage = [&](float* lbuf, int ch) {
#pragma unroll
    for (int round = 0; round < 6; ++round) {
      const int v   = round * 256 + tid;
      const int row = v / 49;
      const int c4  = v - row * 49;
      gload16(xvb + row * Ss + ch * 196 + c4 * 4,
              lbuf + (round * 256 + w * 64) * 4);
    }
    if (tid < 32) {                            // tail: slots 1536..1567 (wave 0)
      const int v   = 1536 + tid;
      const int row = v / 49;
      const int c4  = v - row * 49;
      gload16(xvb + row * Ss + ch * 196 + c4 * 4, lbuf + 1536 * 4);
    }
  };

  stage(&lds[0], 0);
  __syncthreads();

  const int q0   = __builtin_amdgcn_readfirstlane(8 * w);
  const int moff = __builtin_amdgcn_readfirstlane(b * 1024 + q0);
  const float* __restrict__ mrow = mt + moff;   // mrow[k*32 + r], wave-uniform

  for (int ch = 0; ch < 4; ++ch) {
    if (ch < 3) stage(&lds[((ch + 1) & 1) * 6272], ch + 1);   // async, in flight

    if (lane < 49) {
      const float* __restrict__ lbuf = &lds[(ch & 1) * 6272] + lane * 4;
      float4 acc[8] = {};
#pragma unroll
      for (int k = 0; k < 32; ++k) {
        const float4 v = *reinterpret_cast<const float4*>(lbuf + k * 196);
#pragma unroll
        for (int r = 0; r < 8; ++r) {
          const float m = mrow[k * 32 + r];
          acc[r].x += m * v.x; acc[r].y += m * v.y;
          acc[r].z += m * v.z; acc[r].w += m * v.w;
        }
      }
      float* __restrict__ dst = ob + ch * 196 + 4 * lane;
#pragma unroll
      for (int r = 0; r < 8; ++r)
        *reinterpret_cast<float4*>(dst + (size_t)(q0 + r) * Ss) = acc[r];
    }
    __syncthreads();   // drains vmcnt(0): next chunk fully staged
  }
}

}  // namespace

extern "C" void kernel_launch(void* const* d_in, const int* in_sizes, int n_in,
                              void* d_out, int out_size, void* d_ws, size_t ws_size,
                              hipStream_t stream) {
  const float* x  = (const float*)d_in[0];
  const float* xv = (const float*)d_in[1];
  float* out = (float*)d_out;

  // workspace (fp32), ~4.2 MiB total:
  float* part = (float*)d_ws;            // 1024 x 1024
  float* msum = part + 1024 * 1024;      // 16 x 1024
  float* mt   = msum + 16 * 1024;        // 16 x 1024 (k-major softmax weights)

  gram_partial<<<dim3(1024), dim3(256), 0, stream>>>(x, part);
  reduce_c<<<dim3(64), dim3(256), 0, stream>>>(part, msum);
  softmax_b<<<dim3(4), dim3(256), 0, stream>>>(msum, mt);
  pv<<<dim3(1024), dim3(256), 0, stream>>>(xv, mt, out);
}